// Round 10
// baseline (5168.654 us; speedup 1.0000x reference)
//
#include <hip/hip_runtime.h>
#include <hip/hip_bf16.h>
#include <cstdint>

typedef __bf16 bf16_t;
typedef __bf16 bf16x4 __attribute__((ext_vector_type(4)));
typedef __bf16 bf16x8 __attribute__((ext_vector_type(8)));
typedef float f32x4 __attribute__((ext_vector_type(4)));

#define BATCH 4096
#define DIN   1024
#define HID   2048
#define DOUT  1000
#define NITER 50
#define LR    0.001f

#define BM 128
#define BN 128
#define BK 32
#define NBUF 4

// async global -> LDS, 16 B per lane. LDS dest is wave-uniform base + lane*16.
#define GLDS(g, l)                                                        \
    __builtin_amdgcn_global_load_lds(                                     \
        (const __attribute__((address_space(1))) void*)(g),               \
        (__attribute__((address_space(3))) void*)(l), 16, 0, 0)

#define WAITVM(N) asm volatile("s_waitcnt vmcnt(" #N ")" ::: "memory")
#define BAR()     __builtin_amdgcn_s_barrier()
#define SCHEDB()  __builtin_amdgcn_sched_barrier(0)

__device__ __forceinline__ unsigned int bf16_bits(float f) {
    bf16_t h = (bf16_t)f;
    unsigned short s;
    __builtin_memcpy(&s, &h, 2);
    return (unsigned int)s;
}
__device__ __forceinline__ float bf16_val(unsigned short s) {
    unsigned int u = (unsigned int)s << 16;
    float f;
    __builtin_memcpy(&f, &u, 4);
    return f;
}

// ---------------------------------------------------------------------------
// Persistent kernel, SPLIT roles (R7 geometry + R9 register-state).
// Grid = 512 blocks = 32 m-slices x 16 (sub<8: U role, Bt=Wg; sub>=8: Z role,
// Bt=Wc).  512 thr / 8 waves, wave tile 64x32 acc[4][2], single B stream ->
// LDS 64.5 KB -> 2 blocks/CU, 16 waves/CU (R9's occupancy loss fixed).
// VGPR <= 128 via one role-shared state array st[4][2][4] (+eyp for Z).
//   U: u tile in st; e_x' = x - sigmoid(u) -> Adst; energy += e^2
//   Z: z tile in st; e_y packed bf16 in eyp; e_y' = (1+LR)e_y - D;
//      last iter writes y = (1+LR)e_y + z; energy += e_y^2
// Slice barrier: 16 blocks of slice m sync via monotonic device-scope atomic
// (R9-proven release/acquire pattern).  K-loop = R6-proven: NBUF=4, two
// K-tiles per barrier pair, counted vmcnt (steady 4, tail 4->0).
// ---------------------------------------------------------------------------
__global__ __launch_bounds__(512, 4) void pc_persist(
    bf16_t* __restrict__ exA, bf16_t* __restrict__ exB,
    const bf16_t* __restrict__ wg, const bf16_t* __restrict__ wc,
    const float* __restrict__ xin, const float* __restrict__ bias_g,
    const float* __restrict__ bias_o,
    float* __restrict__ yout, float* __restrict__ energy,
    unsigned int* __restrict__ barcnt)
{
    __shared__ __align__(16) bf16_t sA[NBUF][BM * BK];
    __shared__ __align__(16) bf16_t sB[NBUF][BN * BK];
    __shared__ float red[8];

    const int t    = threadIdx.x;
    const int lane = t & 63;
    const int wave = t >> 6;        // 0..7
    const int wm   = wave >> 2;     // 0..1 -> 64 rows
    const int wn   = wave & 3;      // 0..3 -> 32 cols
    const int bid  = blockIdx.x;
    const int m    = bid >> 4;      // 0..31 (slice)
    const int sub  = bid & 15;
    const int role = sub >> 3;      // 0 = U (e_x side), 1 = Z (y side)
    const int n0   = (sub & 7) * BN;
    const int m0   = m * BM;
    const int lr   = lane & 15;
    const int lkb  = (lane >> 4) * 8;
    const int prow = (lane >> 4) * 4;

    const int srow = wave * 16 + (lane >> 2);
    const int scol = (lane & 3) * 8;
    const bf16_t* gB = (role ? wc : wg) + (int64_t)(n0 + srow) * DIN + scol;

    float st[4][2][4];             // U: u tile | Z: z tile (role-shared)
    unsigned int eyp[4][2][2];     // Z only: e_y packed 2x bf16 per reg
    float esum = 0.0f;

    const bf16_t* Asrc = exA;
    bf16_t*       Adst = exB;

    for (int it = 0; it < NITER; ++it) {
        const bool active = !(it == NITER - 1 && role == 0);
        if (active) {
            const bf16_t* gA = Asrc + (int64_t)(m0 + srow) * DIN + scol;
            f32x4 acc[4][2] = {};

            auto stage = [&](int tile, int buf) {
                const int64_t ko = (int64_t)tile * BK;
                GLDS(gA + ko, &sA[buf][wave * 512]);
                GLDS(gB + ko, &sB[buf][wave * 512]);
            };
            auto compute = [&](int buf) {
                bf16x8 af[4], bfr[2];
#pragma unroll
                for (int mi = 0; mi < 4; ++mi)
                    af[mi] = *reinterpret_cast<const bf16x8*>(
                        &sA[buf][(wm * 64 + mi * 16 + lr) * BK + lkb]);
#pragma unroll
                for (int ni = 0; ni < 2; ++ni)
                    bfr[ni] = *reinterpret_cast<const bf16x8*>(
                        &sB[buf][(wn * 32 + ni * 16 + lr) * BK + lkb]);
#pragma unroll
                for (int mi = 0; mi < 4; ++mi)
#pragma unroll
                    for (int ni = 0; ni < 2; ++ni)
                        acc[mi][ni] = __builtin_amdgcn_mfma_f32_16x16x32_bf16(
                            af[mi], bfr[ni], acc[mi][ni], 0, 0, 0);
            };

            const int npairs = (DIN / BK) / 2;   // 16
            stage(0, 0); stage(1, 1); stage(2, 2); stage(3, 3);  // 8 loads
            for (int p = 0; p < npairs - 2; ++p) {
                const int t0 = 2 * p;
                WAITVM(4);                 // pair p landed; pair p+1 flying
                BAR();
                SCHEDB();
                compute(t0 & 3);
                compute((t0 + 1) & 3);
                BAR();
                stage(t0 + 4, t0 & 3);     // back to 8 in flight; never 0
                stage(t0 + 5, (t0 + 1) & 3);
            }
            {
                const int t0 = 2 * npairs - 4;
                WAITVM(4); BAR(); SCHEDB();
                compute(t0 & 3); compute((t0 + 1) & 3);
            }
            {
                const int t0 = 2 * npairs - 2;
                WAITVM(0); BAR(); SCHEDB();
                compute(t0 & 3); compute((t0 + 1) & 3);
            }

            // epilogue: C mapping col=lane&15, row=(lane>>4)*4+j
#pragma unroll
            for (int mi = 0; mi < 4; ++mi) {
#pragma unroll
                for (int ni = 0; ni < 2; ++ni) {
                    const int col = n0 + wn * 32 + ni * 16 + lr;
#pragma unroll
                    for (int j = 0; j < 4; ++j) {
                        const int row = m0 + wm * 64 + mi * 16 + prow + j;
                        const float D = LR * acc[mi][ni][j];
                        if (role == 0) {
                            const int64_t idx = (int64_t)row * DIN + col;
                            const float base = (it == 0) ? bias_g[col]
                                                         : st[mi][ni][j];
                            const float un = base + D;
                            st[mi][ni][j] = un;
                            const float xp = 1.0f / (1.0f + __expf(-un));
                            const float e  = xin[idx] - xp;
                            Adst[idx] = (bf16_t)e;
                            esum += e * e;
                        } else if (col < DOUT) {
                            const float base = (it == 0) ? bias_o[col]
                                                         : st[mi][ni][j];
                            const float zn = base + D;
                            st[mi][ni][j] = zn;
                            const unsigned int w = eyp[mi][ni][j >> 1];
                            const float eyold = bf16_val(
                                (j & 1) ? (unsigned short)(w >> 16)
                                        : (unsigned short)(w & 0xFFFFu));
                            const float eyn =
                                (it == 0) ? -zn : (1.0f + LR) * eyold - D;
                            if (it == NITER - 1) {
                                yout[(int64_t)row * DOUT + col] =
                                    (1.0f + LR) * eyn + zn;
                            } else {
                                const unsigned int b = bf16_bits(eyn);
                                eyp[mi][ni][j >> 1] =
                                    (j & 1) ? ((w & 0x0000FFFFu) | (b << 16))
                                            : ((w & 0xFFFF0000u) | b);
                            }
                            esum += eyn * eyn;
                        }
                    }
                }
            }
        }

        // ---- slice barrier: 16 blocks sharing m-slice, monotonic counter ---
        if (it != NITER - 1) {
            __syncthreads();
            if (t == 0) {
                __threadfence();                       // publish e_x' stores
                atomicAdd(&barcnt[m], 1u);
                const unsigned int tgt = 16u * (unsigned int)(it + 1);
                while (atomicAdd(&barcnt[m], 0u) < tgt)
                    __builtin_amdgcn_s_sleep(8);
                __threadfence();                       // acquire peers' stores
            }
            __syncthreads();
        }
        bf16_t* tmp = Adst; Adst = (bf16_t*)Asrc; Asrc = tmp;
    }

    // energy reduction: esum accumulated over all iterations
#pragma unroll
    for (int off = 32; off; off >>= 1) esum += __shfl_down(esum, off, 64);
    if (lane == 0) red[wave] = esum;
    __syncthreads();
    if (t == 0) {
        float s = 0.0f;
#pragma unroll
        for (int w = 0; w < 8; ++w) s += red[w];
        atomicAdd(energy, s);
    }
}

// ---------------------------------------------------------------------------
// setup: Wg = W_rec^T W_rec (role 0), Wc = W_out W_rec (role 1); K = 2048.
// R6-proven GEMM core, plain C-store epilogue.  Runs once.
// ---------------------------------------------------------------------------
__global__ __launch_bounds__(512) void setup_gemm(
    const bf16_t* __restrict__ wrecT, const bf16_t* __restrict__ woutP,
    bf16_t* __restrict__ wg, bf16_t* __restrict__ wc)
{
    __shared__ __align__(16) bf16_t sA[NBUF][BM * BK];
    __shared__ __align__(16) bf16_t sB[NBUF][BN * BK];

    const int t    = threadIdx.x;
    const int lane = t & 63;
    const int wave = t >> 6;
    const int wm   = wave >> 2;
    const int wn   = wave & 3;
    const int m0   = blockIdx.x * BM;
    const int role = (int)blockIdx.y >= 8;
    const int n0   = ((int)blockIdx.y & 7) * BN;
    const int lr   = lane & 15;
    const int lkb  = (lane >> 4) * 8;
    const int prow = (lane >> 4) * 4;

    f32x4 acc[4][2] = {};

    const int srow = wave * 16 + (lane >> 2);
    const int scol = (lane & 3) * 8;
    const bf16_t* gA = (role ? woutP : wrecT) + (int64_t)(m0 + srow) * HID + scol;
    const bf16_t* gB = wrecT + (int64_t)(n0 + srow) * HID + scol;

    auto stage = [&](int tile, int buf) {
        const int64_t ko = (int64_t)tile * BK;
        GLDS(gA + ko, &sA[buf][wave * 512]);
        GLDS(gB + ko, &sB[buf][wave * 512]);
    };
    auto compute = [&](int buf) {
        bf16x8 af[4], bfr[2];
#pragma unroll
        for (int mi = 0; mi < 4; ++mi)
            af[mi] = *reinterpret_cast<const bf16x8*>(
                &sA[buf][(wm * 64 + mi * 16 + lr) * BK + lkb]);
#pragma unroll
        for (int ni = 0; ni < 2; ++ni)
            bfr[ni] = *reinterpret_cast<const bf16x8*>(
                &sB[buf][(wn * 32 + ni * 16 + lr) * BK + lkb]);
#pragma unroll
        for (int mi = 0; mi < 4; ++mi)
#pragma unroll
            for (int ni = 0; ni < 2; ++ni)
                acc[mi][ni] = __builtin_amdgcn_mfma_f32_16x16x32_bf16(
                    af[mi], bfr[ni], acc[mi][ni], 0, 0, 0);
    };

    const int npairs = (HID / BK) / 2;   // 32
    stage(0, 0); stage(1, 1); stage(2, 2); stage(3, 3);
    for (int p = 0; p < npairs - 2; ++p) {
        const int t0 = 2 * p;
        WAITVM(4); BAR(); SCHEDB();
        compute(t0 & 3); compute((t0 + 1) & 3);
        BAR();
        stage(t0 + 4, t0 & 3); stage(t0 + 5, (t0 + 1) & 3);
    }
    {
        const int t0 = 2 * npairs - 4;
        WAITVM(4); BAR(); SCHEDB();
        compute(t0 & 3); compute((t0 + 1) & 3);
    }
    {
        const int t0 = 2 * npairs - 2;
        WAITVM(0); BAR(); SCHEDB();
        compute(t0 & 3); compute((t0 + 1) & 3);
    }

    bf16_t* cout = role ? wc : wg;
#pragma unroll
    for (int mi = 0; mi < 4; ++mi)
#pragma unroll
        for (int ni = 0; ni < 2; ++ni) {
            const int col = n0 + wn * 32 + ni * 16 + lr;
#pragma unroll
            for (int j = 0; j < 4; ++j) {
                const int row = m0 + wm * 64 + mi * 16 + prow + j;
                cout[(int64_t)row * 1024 + col] = (bf16_t)acc[mi][ni][j];
            }
        }
}

// W_rec [HID][DIN] f32 -> bf16 transpose [DIN][HID]
__global__ void conv_wrec(const float* __restrict__ W, bf16_t* __restrict__ WbT)
{
    __shared__ float tile[32][33];
    const int tx = threadIdx.x & 31;
    const int ty = threadIdx.x >> 5;
    const int c0 = blockIdx.x * 32;
    const int r0 = blockIdx.y * 32;
#pragma unroll
    for (int rr = ty; rr < 32; rr += 8)
        tile[rr][tx] = W[(int64_t)(r0 + rr) * DIN + c0 + tx];
    __syncthreads();
#pragma unroll
    for (int rr = ty; rr < 32; rr += 8)
        WbT[(int64_t)(c0 + rr) * HID + r0 + tx] = (bf16_t)tile[tx][rr];
}

// W_out [DOUT][HID] f32 -> bf16 [1024][HID], rows >= DOUT zero-padded
__global__ void conv_wout(const float* __restrict__ W, bf16_t* __restrict__ Wb)
{
    const int i = blockIdx.x * 256 + threadIdx.x;
    const int r = i >> 11;
    const int c = i & 2047;
    Wb[i] = (r < DOUT) ? (bf16_t)W[(int64_t)r * HID + c] : (bf16_t)0.0f;
}

// iteration 0: e_x_0 = x - sigmoid(b_gen), + its energy term
__global__ void ex0_kernel(const float* __restrict__ x,
                           const float* __restrict__ bias_g,
                           bf16_t* __restrict__ ex, float* __restrict__ energy)
{
    __shared__ float red[4];
    const int t = threadIdx.x, lane = t & 63, wave = t >> 6;
    const int i = (blockIdx.x * 256 + t) * 4;
    const int c0 = i & (DIN - 1);
    const float4 v = *reinterpret_cast<const float4*>(&x[i]);
    float e[4];
    const float b0 = bias_g[c0], b1 = bias_g[c0 + 1],
                b2 = bias_g[c0 + 2], b3 = bias_g[c0 + 3];
    e[0] = v.x - 1.0f / (1.0f + __expf(-b0));
    e[1] = v.y - 1.0f / (1.0f + __expf(-b1));
    e[2] = v.z - 1.0f / (1.0f + __expf(-b2));
    e[3] = v.w - 1.0f / (1.0f + __expf(-b3));
    bf16x4 o = {(bf16_t)e[0], (bf16_t)e[1], (bf16_t)e[2], (bf16_t)e[3]};
    *reinterpret_cast<bf16x4*>(&ex[i]) = o;
    float esum = e[0]*e[0] + e[1]*e[1] + e[2]*e[2] + e[3]*e[3];
#pragma unroll
    for (int off = 32; off; off >>= 1) esum += __shfl_down(esum, off, 64);
    if (lane == 0) red[wave] = esum;
    __syncthreads();
    if (t == 0) atomicAdd(energy, red[0] + red[1] + red[2] + red[3]);
}

__global__ void finalize_kernel(const float* __restrict__ energy,
                                float* __restrict__ out)
{
    out[0] = energy[0] * (1.0f / ((float)BATCH * (float)NITER));
}

extern "C" void kernel_launch(void* const* d_in, const int* in_sizes, int n_in,
                              void* d_out, int out_size, void* d_ws, size_t ws_size,
                              hipStream_t stream)
{
    (void)in_sizes; (void)n_in; (void)out_size; (void)ws_size;
    const float* x        = (const float*)d_in[0];
    const float* W_rec    = (const float*)d_in[1];
    const float* W_out    = (const float*)d_in[2];
    const float* bias_out = (const float*)d_in[3];
    const float* bias_gen = (const float*)d_in[4];
    float* y = (float*)d_out; // [BATCH*DOUT] then [1] energy

    char* ws = (char*)d_ws;
    size_t off = 0;
    bf16_t* exA   = (bf16_t*)(ws + off);  off += (size_t)BATCH * DIN * 2;   // 8 MB
    bf16_t* exB   = (bf16_t*)(ws + off);  off += (size_t)BATCH * DIN * 2;   // 8 MB
    bf16_t* wrecT = (bf16_t*)(ws + off);  off += (size_t)DIN * HID * 2;     // 4 MB
    bf16_t* woutP = (bf16_t*)(ws + off);  off += (size_t)1024 * HID * 2;    // 4 MB
    bf16_t* wg    = (bf16_t*)(ws + off);  off += (size_t)1024 * 1024 * 2;   // 2 MB
    bf16_t* wc    = (bf16_t*)(ws + off);  off += (size_t)1024 * 1024 * 2;   // 2 MB
    float* energy = (float*)(ws + off);                                     // +256 B
    unsigned int* barcnt = (unsigned int*)(ws + off + 64);  // 32 counters

    // zero energy + barrier counters (fresh every call -> deterministic)
    hipMemsetAsync(energy, 0, 256, stream);

    conv_wrec<<<dim3(DIN / 32, HID / 32), 256, 0, stream>>>(W_rec, wrecT);
    conv_wout<<<(1024 * HID) / 256, 256, 0, stream>>>(W_out, woutP);
    setup_gemm<<<dim3(8, 16), 512, 0, stream>>>(wrecT, woutP, wg, wc);
    ex0_kernel<<<(BATCH * DIN) / 1024, 256, 0, stream>>>(x, bias_gen, exA, energy);

    pc_persist<<<dim3(512), dim3(512), 0, stream>>>(
        exA, exB, wg, wc, x, bias_gen, bias_out, y, energy, barcnt);

    finalize_kernel<<<1, 1, 0, stream>>>(energy, y + (size_t)BATCH * DOUT);
}

// Round 11
// 3229.933 us; speedup vs baseline: 1.6002x; 1.6002x over previous
//
#include <hip/hip_runtime.h>
#include <hip/hip_bf16.h>
#include <cstdint>

typedef __bf16 bf16_t;
typedef __bf16 bf16x4 __attribute__((ext_vector_type(4)));
typedef __bf16 bf16x8 __attribute__((ext_vector_type(8)));
typedef float f32x4 __attribute__((ext_vector_type(4)));

#define BATCH 4096
#define DIN   1024
#define HID   2048
#define DOUT  1000
#define NITER 50
#define LR    0.001f

#define BM 128
#define BN 128
#define BK 32
#define NBUF 4

// async global -> LDS, 16 B per lane. LDS dest is wave-uniform base + lane*16.
#define GLDS(g, l)                                                        \
    __builtin_amdgcn_global_load_lds(                                     \
        (const __attribute__((address_space(1))) void*)(g),               \
        (__attribute__((address_space(3))) void*)(l), 16, 0, 0)

#define WAITVM(N) asm volatile("s_waitcnt vmcnt(" #N ")" ::: "memory")
#define BAR()     __builtin_amdgcn_s_barrier()
#define SCHEDB()  __builtin_amdgcn_sched_barrier(0)

__device__ __forceinline__ unsigned int bf16_bits(float f) {
    bf16_t h = (bf16_t)f;
    unsigned short s;
    __builtin_memcpy(&s, &h, 2);
    return (unsigned int)s;
}
__device__ __forceinline__ float bf16_val(unsigned short s) {
    unsigned int u = (unsigned int)s << 16;
    float f;
    __builtin_memcpy(&f, &u, 4);
    return f;
}

// ---------------------------------------------------------------------------
// Persistent kernel, MERGED roles at full TLP (fixes R9's 1-block/CU TLP loss
// and R10's launch_bounds-induced spill).
// Grid = 256 blocks x 1024 thr (16 waves) = 1 block/CU (96 KB LDS), grid ==
// #CUs -> co-residency GUARANTEED (no 512-block cliff, no cooperative API).
// Block b = (m = b>>3, n = b&7); n==XCD under round-robin -> Wg/Wc panel
// (512 KB) stays L2-resident per XCD.
//   waves 0-7  (half=0): U role, B = Wg; u tile in regs; e_x'=x-sig(u)->Adst
//   waves 8-15 (half=1): Z role, B = Wc; z in regs, e_y packed bf16 in regs
// ONE shared A-stage (e_x tile staged once for both halves).
// Per-thread state = one role only (~120 VGPR); __launch_bounds__(1024)
// alone caps VGPR at 128 (16-wave block must fit 4 waves/SIMD) -- avoids the
// R10 2nd-arg misinterpretation (64-cap spill).
// K-loop: counted vmcnt, 2 tiles/barrier-pair; role-asymmetric load counts
// (U: 4/pair [A+BU], Z: 2/pair [BZ]) -> role-branched WAITVM(4)/(2), tail 0.
// Slice barrier: 8 blocks (m,*) via monotonic device-scope atomic (proven).
// ---------------------------------------------------------------------------
__global__ __launch_bounds__(1024) void pc_persist(
    bf16_t* __restrict__ exA, bf16_t* __restrict__ exB,
    const bf16_t* __restrict__ wg, const bf16_t* __restrict__ wc,
    const float* __restrict__ xin, const float* __restrict__ bias_g,
    const float* __restrict__ bias_o,
    float* __restrict__ yout, float* __restrict__ energy,
    unsigned int* __restrict__ barcnt)
{
    __shared__ __align__(16) bf16_t sA [NBUF][BM * BK];
    __shared__ __align__(16) bf16_t sBU[NBUF][BN * BK];
    __shared__ __align__(16) bf16_t sBZ[NBUF][BN * BK];
    __shared__ float red[16];

    const int t    = threadIdx.x;
    const int lane = t & 63;
    const int wave = t >> 6;        // 0..15
    const int half = wave >> 3;     // 0 = U role, 1 = Z role
    const int w8   = wave & 7;      // wave id within role-half
    const int wm   = w8 >> 2;       // 0..1 -> 64 rows
    const int wn   = w8 & 3;        // 0..3 -> 32 cols
    const int bid  = blockIdx.x;
    const int m    = bid >> 3;      // 0..31 (slice)
    const int n    = bid & 7;       // 0..7  (== XCD under round-robin)
    const int m0   = m * BM;
    const int n0   = n * BN;
    const int lr   = lane & 15;
    const int lkb  = (lane >> 4) * 8;
    const int prow = (lane >> 4) * 4;

    const int srow = w8 * 16 + (lane >> 2);
    const int scol = (lane & 3) * 8;
    const bf16_t* gBu = wg + (int64_t)(n0 + srow) * DIN + scol;  // U staging
    const bf16_t* gBz = wc + (int64_t)(n0 + srow) * DIN + scol;  // Z staging
    // compute-side B base: role-selected once (both are LDS)
    const bf16_t* const sBbase = half ? &sBZ[0][0] : &sBU[0][0];

    float st[4][2][4];             // U: u tile | Z: z tile (one role/thread)
    unsigned int eyp[4][2][2];     // Z only: e_y packed 2x bf16 per reg
    float esum = 0.0f;

    const bf16_t* Asrc = exA;
    bf16_t*       Adst = exB;

    for (int it = 0; it < NITER; ++it) {
        const bf16_t* gA = Asrc + (int64_t)(m0 + srow) * DIN + scol;
        f32x4 acc[4][2] = {};

        auto stage = [&](int tile, int buf) {
            const int64_t ko = (int64_t)tile * BK;
            if (half == 0) {
                GLDS(gA  + ko, &sA [buf][w8 * 512]);
                GLDS(gBu + ko, &sBU[buf][w8 * 512]);
            } else {
                GLDS(gBz + ko, &sBZ[buf][w8 * 512]);
            }
        };
        auto compute = [&](int buf) {
            bf16x8 af[4], bfr[2];
#pragma unroll
            for (int mi = 0; mi < 4; ++mi)
                af[mi] = *reinterpret_cast<const bf16x8*>(
                    &sA[buf][(wm * 64 + mi * 16 + lr) * BK + lkb]);
#pragma unroll
            for (int ni = 0; ni < 2; ++ni)
                bfr[ni] = *reinterpret_cast<const bf16x8*>(
                    &sBbase[buf * (BN * BK) +
                            (wn * 32 + ni * 16 + lr) * BK + lkb]);
#pragma unroll
            for (int mi = 0; mi < 4; ++mi)
#pragma unroll
                for (int ni = 0; ni < 2; ++ni)
                    acc[mi][ni] = __builtin_amdgcn_mfma_f32_16x16x32_bf16(
                        af[mi], bfr[ni], acc[mi][ni], 0, 0, 0);
        };

        const int npairs = (DIN / BK) / 2;   // 16
        stage(0, 0); stage(1, 1); stage(2, 2); stage(3, 3);
        for (int p = 0; p < npairs - 2; ++p) {
            const int t0 = 2 * p;
            if (half == 0) { WAITVM(4); } else { WAITVM(2); }
            BAR();
            SCHEDB();
            compute(t0 & 3);
            compute((t0 + 1) & 3);
            BAR();
            stage(t0 + 4, t0 & 3);       // never drain vmcnt to 0 in loop
            stage(t0 + 5, (t0 + 1) & 3);
        }
        {
            const int t0 = 2 * npairs - 4;
            if (half == 0) { WAITVM(4); } else { WAITVM(2); }
            BAR(); SCHEDB();
            compute(t0 & 3); compute((t0 + 1) & 3);
        }
        {
            const int t0 = 2 * npairs - 2;
            WAITVM(0); BAR(); SCHEDB();
            compute(t0 & 3); compute((t0 + 1) & 3);
        }

        // epilogue: C mapping col=lane&15, row=(lane>>4)*4+j
#pragma unroll
        for (int mi = 0; mi < 4; ++mi) {
#pragma unroll
            for (int ni = 0; ni < 2; ++ni) {
                const int col = n0 + wn * 32 + ni * 16 + lr;
#pragma unroll
                for (int j = 0; j < 4; ++j) {
                    const int row = m0 + wm * 64 + mi * 16 + prow + j;
                    const float D = LR * acc[mi][ni][j];
                    if (half == 0) {
                        if (it != NITER - 1) {   // e_x^(50) not needed/counted
                            const int64_t idx = (int64_t)row * DIN + col;
                            const float base = (it == 0) ? bias_g[col]
                                                         : st[mi][ni][j];
                            const float un = base + D;
                            st[mi][ni][j] = un;
                            const float xp = 1.0f / (1.0f + __expf(-un));
                            const float e  = xin[idx] - xp;
                            Adst[idx] = (bf16_t)e;
                            esum += e * e;
                        }
                    } else if (col < DOUT) {
                        const float base = (it == 0) ? bias_o[col]
                                                     : st[mi][ni][j];
                        const float zn = base + D;
                        st[mi][ni][j] = zn;
                        const unsigned int w = eyp[mi][ni][j >> 1];
                        const float eyold = bf16_val(
                            (j & 1) ? (unsigned short)(w >> 16)
                                    : (unsigned short)(w & 0xFFFFu));
                        const float eyn =
                            (it == 0) ? -zn : (1.0f + LR) * eyold - D;
                        if (it == NITER - 1) {
                            yout[(int64_t)row * DOUT + col] =
                                (1.0f + LR) * eyn + zn;
                        } else {
                            const unsigned int b = bf16_bits(eyn);
                            eyp[mi][ni][j >> 1] =
                                (j & 1) ? ((w & 0x0000FFFFu) | (b << 16))
                                        : ((w & 0xFFFF0000u) | b);
                        }
                        esum += eyn * eyn;
                    }
                }
            }
        }

        // ---- slice barrier: 8 blocks sharing m-slice, monotonic counter ---
        if (it != NITER - 1) {
            __syncthreads();
            if (t == 0) {
                __threadfence();                       // publish e_x' stores
                atomicAdd(&barcnt[m], 1u);
                const unsigned int tgt = 8u * (unsigned int)(it + 1);
                while (atomicAdd(&barcnt[m], 0u) < tgt)
                    __builtin_amdgcn_s_sleep(8);
                __threadfence();                       // acquire peers' stores
            }
            __syncthreads();
        }
        bf16_t* tmp = Adst; Adst = (bf16_t*)Asrc; Asrc = tmp;
    }

    // energy reduction: esum accumulated over all iterations
#pragma unroll
    for (int off = 32; off; off >>= 1) esum += __shfl_down(esum, off, 64);
    if (lane == 0) red[wave] = esum;
    __syncthreads();
    if (t == 0) {
        float s = 0.0f;
#pragma unroll
        for (int w = 0; w < 16; ++w) s += red[w];
        atomicAdd(energy, s);
    }
}

// ---------------------------------------------------------------------------
// setup: Wg = W_rec^T W_rec (role 0), Wc = W_out W_rec (role 1); K = 2048.
// R6-proven GEMM core, plain C-store epilogue.  Runs once.
// ---------------------------------------------------------------------------
__global__ __launch_bounds__(512) void setup_gemm(
    const bf16_t* __restrict__ wrecT, const bf16_t* __restrict__ woutP,
    bf16_t* __restrict__ wg, bf16_t* __restrict__ wc)
{
    __shared__ __align__(16) bf16_t sA[NBUF][BM * BK];
    __shared__ __align__(16) bf16_t sB[NBUF][BN * BK];

    const int t    = threadIdx.x;
    const int lane = t & 63;
    const int wave = t >> 6;
    const int wm   = wave >> 2;
    const int wn   = wave & 3;
    const int m0   = blockIdx.x * BM;
    const int role = (int)blockIdx.y >= 8;
    const int n0   = ((int)blockIdx.y & 7) * BN;
    const int lr   = lane & 15;
    const int lkb  = (lane >> 4) * 8;
    const int prow = (lane >> 4) * 4;

    f32x4 acc[4][2] = {};

    const int srow = wave * 16 + (lane >> 2);
    const int scol = (lane & 3) * 8;
    const bf16_t* gA = (role ? woutP : wrecT) + (int64_t)(m0 + srow) * HID + scol;
    const bf16_t* gB = wrecT + (int64_t)(n0 + srow) * HID + scol;

    auto stage = [&](int tile, int buf) {
        const int64_t ko = (int64_t)tile * BK;
        GLDS(gA + ko, &sA[buf][wave * 512]);
        GLDS(gB + ko, &sB[buf][wave * 512]);
    };
    auto compute = [&](int buf) {
        bf16x8 af[4], bfr[2];
#pragma unroll
        for (int mi = 0; mi < 4; ++mi)
            af[mi] = *reinterpret_cast<const bf16x8*>(
                &sA[buf][(wm * 64 + mi * 16 + lr) * BK + lkb]);
#pragma unroll
        for (int ni = 0; ni < 2; ++ni)
            bfr[ni] = *reinterpret_cast<const bf16x8*>(
                &sB[buf][(wn * 32 + ni * 16 + lr) * BK + lkb]);
#pragma unroll
        for (int mi = 0; mi < 4; ++mi)
#pragma unroll
            for (int ni = 0; ni < 2; ++ni)
                acc[mi][ni] = __builtin_amdgcn_mfma_f32_16x16x32_bf16(
                    af[mi], bfr[ni], acc[mi][ni], 0, 0, 0);
    };

    const int npairs = (HID / BK) / 2;   // 32
    stage(0, 0); stage(1, 1); stage(2, 2); stage(3, 3);
    for (int p = 0; p < npairs - 2; ++p) {
        const int t0 = 2 * p;
        WAITVM(4); BAR(); SCHEDB();
        compute(t0 & 3); compute((t0 + 1) & 3);
        BAR();
        stage(t0 + 4, t0 & 3); stage(t0 + 5, (t0 + 1) & 3);
    }
    {
        const int t0 = 2 * npairs - 4;
        WAITVM(4); BAR(); SCHEDB();
        compute(t0 & 3); compute((t0 + 1) & 3);
    }
    {
        const int t0 = 2 * npairs - 2;
        WAITVM(0); BAR(); SCHEDB();
        compute(t0 & 3); compute((t0 + 1) & 3);
    }

    bf16_t* cout = role ? wc : wg;
#pragma unroll
    for (int mi = 0; mi < 4; ++mi)
#pragma unroll
        for (int ni = 0; ni < 2; ++ni) {
            const int col = n0 + wn * 32 + ni * 16 + lr;
#pragma unroll
            for (int j = 0; j < 4; ++j) {
                const int row = m0 + wm * 64 + mi * 16 + prow + j;
                cout[(int64_t)row * 1024 + col] = (bf16_t)acc[mi][ni][j];
            }
        }
}

// W_rec [HID][DIN] f32 -> bf16 transpose [DIN][HID]
__global__ void conv_wrec(const float* __restrict__ W, bf16_t* __restrict__ WbT)
{
    __shared__ float tile[32][33];
    const int tx = threadIdx.x & 31;
    const int ty = threadIdx.x >> 5;
    const int c0 = blockIdx.x * 32;
    const int r0 = blockIdx.y * 32;
#pragma unroll
    for (int rr = ty; rr < 32; rr += 8)
        tile[rr][tx] = W[(int64_t)(r0 + rr) * DIN + c0 + tx];
    __syncthreads();
#pragma unroll
    for (int rr = ty; rr < 32; rr += 8)
        WbT[(int64_t)(c0 + rr) * HID + r0 + tx] = (bf16_t)tile[tx][rr];
}

// W_out [DOUT][HID] f32 -> bf16 [1024][HID], rows >= DOUT zero-padded
__global__ void conv_wout(const float* __restrict__ W, bf16_t* __restrict__ Wb)
{
    const int i = blockIdx.x * 256 + threadIdx.x;
    const int r = i >> 11;
    const int c = i & 2047;
    Wb[i] = (r < DOUT) ? (bf16_t)W[(int64_t)r * HID + c] : (bf16_t)0.0f;
}

// iteration 0: e_x_0 = x - sigmoid(b_gen), + its energy term
__global__ void ex0_kernel(const float* __restrict__ x,
                           const float* __restrict__ bias_g,
                           bf16_t* __restrict__ ex, float* __restrict__ energy)
{
    __shared__ float red[4];
    const int t = threadIdx.x, lane = t & 63, wave = t >> 6;
    const int i = (blockIdx.x * 256 + t) * 4;
    const int c0 = i & (DIN - 1);
    const float4 v = *reinterpret_cast<const float4*>(&x[i]);
    float e[4];
    const float b0 = bias_g[c0], b1 = bias_g[c0 + 1],
                b2 = bias_g[c0 + 2], b3 = bias_g[c0 + 3];
    e[0] = v.x - 1.0f / (1.0f + __expf(-b0));
    e[1] = v.y - 1.0f / (1.0f + __expf(-b1));
    e[2] = v.z - 1.0f / (1.0f + __expf(-b2));
    e[3] = v.w - 1.0f / (1.0f + __expf(-b3));
    bf16x4 o = {(bf16_t)e[0], (bf16_t)e[1], (bf16_t)e[2], (bf16_t)e[3]};
    *reinterpret_cast<bf16x4*>(&ex[i]) = o;
    float esum = e[0]*e[0] + e[1]*e[1] + e[2]*e[2] + e[3]*e[3];
#pragma unroll
    for (int off = 32; off; off >>= 1) esum += __shfl_down(esum, off, 64);
    if (lane == 0) red[wave] = esum;
    __syncthreads();
    if (t == 0) atomicAdd(energy, red[0] + red[1] + red[2] + red[3]);
}

__global__ void finalize_kernel(const float* __restrict__ energy,
                                float* __restrict__ out)
{
    out[0] = energy[0] * (1.0f / ((float)BATCH * (float)NITER));
}

extern "C" void kernel_launch(void* const* d_in, const int* in_sizes, int n_in,
                              void* d_out, int out_size, void* d_ws, size_t ws_size,
                              hipStream_t stream)
{
    (void)in_sizes; (void)n_in; (void)out_size; (void)ws_size;
    const float* x        = (const float*)d_in[0];
    const float* W_rec    = (const float*)d_in[1];
    const float* W_out    = (const float*)d_in[2];
    const float* bias_out = (const float*)d_in[3];
    const float* bias_gen = (const float*)d_in[4];
    float* y = (float*)d_out; // [BATCH*DOUT] then [1] energy

    char* ws = (char*)d_ws;
    size_t off = 0;
    bf16_t* exA   = (bf16_t*)(ws + off);  off += (size_t)BATCH * DIN * 2;   // 8 MB
    bf16_t* exB   = (bf16_t*)(ws + off);  off += (size_t)BATCH * DIN * 2;   // 8 MB
    bf16_t* wrecT = (bf16_t*)(ws + off);  off += (size_t)DIN * HID * 2;     // 4 MB
    bf16_t* woutP = (bf16_t*)(ws + off);  off += (size_t)1024 * HID * 2;    // 4 MB
    bf16_t* wg    = (bf16_t*)(ws + off);  off += (size_t)1024 * 1024 * 2;   // 2 MB
    bf16_t* wc    = (bf16_t*)(ws + off);  off += (size_t)1024 * 1024 * 2;   // 2 MB
    float* energy = (float*)(ws + off);                                     // +256 B
    unsigned int* barcnt = (unsigned int*)(ws + off + 64);  // 32 counters

    // zero energy + barrier counters (fresh every call -> deterministic)
    hipMemsetAsync(energy, 0, 256, stream);

    conv_wrec<<<dim3(DIN / 32, HID / 32), 256, 0, stream>>>(W_rec, wrecT);
    conv_wout<<<(1024 * HID) / 256, 256, 0, stream>>>(W_out, woutP);
    setup_gemm<<<dim3(8, 16), 512, 0, stream>>>(wrecT, woutP, wg, wc);
    ex0_kernel<<<(BATCH * DIN) / 1024, 256, 0, stream>>>(x, bias_gen, exA, energy);

    pc_persist<<<dim3(256), dim3(1024), 0, stream>>>(
        exA, exB, wg, wc, x, bias_gen, bias_out, y, energy, barcnt);

    finalize_kernel<<<1, 1, 0, stream>>>(energy, y + (size_t)BATCH * DOUT);
}

// Round 12
// 3215.681 us; speedup vs baseline: 1.6073x; 1.0044x over previous
//
#include <hip/hip_runtime.h>
#include <hip/hip_bf16.h>
#include <cstdint>

typedef __bf16 bf16_t;
typedef __bf16 bf16x4 __attribute__((ext_vector_type(4)));
typedef __bf16 bf16x8 __attribute__((ext_vector_type(8)));
typedef float f32x4 __attribute__((ext_vector_type(4)));

#define BATCH 4096
#define DIN   1024
#define HID   2048
#define DOUT  1000
#define NITER 50
#define LR    0.001f

#define BM 128
#define BN 128
#define BK 32
#define NBUF 4

// async global -> LDS, 16 B per lane. LDS dest is wave-uniform base + lane*16.
#define GLDS(g, l)                                                        \
    __builtin_amdgcn_global_load_lds(                                     \
        (const __attribute__((address_space(1))) void*)(g),               \
        (__attribute__((address_space(3))) void*)(l), 16, 0, 0)

#define WAITVM(N) asm volatile("s_waitcnt vmcnt(" #N ")" ::: "memory")
#define BAR()     __builtin_amdgcn_s_barrier()
#define SCHEDB()  __builtin_amdgcn_sched_barrier(0)

__device__ __forceinline__ unsigned int bf16_bits(float f) {
    bf16_t h = (bf16_t)f;
    unsigned short s;
    __builtin_memcpy(&s, &h, 2);
    return (unsigned int)s;
}
__device__ __forceinline__ float bf16_val(unsigned short s) {
    unsigned int u = (unsigned int)s << 16;
    float f;
    __builtin_memcpy(&f, &u, 4);
    return f;
}

// ---------------------------------------------------------------------------
// Persistent kernel, MERGED roles at full TLP.  Identical to R11 except
// __launch_bounds__(1024, 1): R10/R11 showed the 2nd arg (and the default)
// behaves as a max-occupancy target (blocks/CU) -> 8 waves/SIMD -> 64-VGPR
// cap -> ~120-reg state spilled to scratch (FETCH 3.1 GB/dispatch, MfmaUtil
// 11%).  Declaring 1 block/CU (16 waves = 4 waves/SIMD) raises the cap to
// 128 VGPR under either documented semantics -> no spill.
// Grid = 256 blocks x 1024 thr = 1 block/CU (96 KB LDS), co-residency by
// construction.  waves 0-7: U role (B=Wg, u in regs, e_x'->Adst);
// waves 8-15: Z role (B=Wc, z + packed e_y in regs).  One shared A-stage.
// K-loop: counted vmcnt, 2 tiles/barrier-pair, role-branched WAITVM.
// Slice barrier: 8 blocks via monotonic device-scope atomic (proven).
// ---------------------------------------------------------------------------
__global__ __launch_bounds__(1024, 1) void pc_persist(
    bf16_t* __restrict__ exA, bf16_t* __restrict__ exB,
    const bf16_t* __restrict__ wg, const bf16_t* __restrict__ wc,
    const float* __restrict__ xin, const float* __restrict__ bias_g,
    const float* __restrict__ bias_o,
    float* __restrict__ yout, float* __restrict__ energy,
    unsigned int* __restrict__ barcnt)
{
    __shared__ __align__(16) bf16_t sA [NBUF][BM * BK];
    __shared__ __align__(16) bf16_t sBU[NBUF][BN * BK];
    __shared__ __align__(16) bf16_t sBZ[NBUF][BN * BK];
    __shared__ float red[16];

    const int t    = threadIdx.x;
    const int lane = t & 63;
    const int wave = t >> 6;        // 0..15
    const int half = wave >> 3;     // 0 = U role, 1 = Z role
    const int w8   = wave & 7;      // wave id within role-half
    const int wm   = w8 >> 2;       // 0..1 -> 64 rows
    const int wn   = w8 & 3;        // 0..3 -> 32 cols
    const int bid  = blockIdx.x;
    const int m    = bid >> 3;      // 0..31 (slice)
    const int n    = bid & 7;       // 0..7  (== XCD under round-robin)
    const int m0   = m * BM;
    const int n0   = n * BN;
    const int lr   = lane & 15;
    const int lkb  = (lane >> 4) * 8;
    const int prow = (lane >> 4) * 4;

    const int srow = w8 * 16 + (lane >> 2);
    const int scol = (lane & 3) * 8;
    const bf16_t* gBu = wg + (int64_t)(n0 + srow) * DIN + scol;  // U staging
    const bf16_t* gBz = wc + (int64_t)(n0 + srow) * DIN + scol;  // Z staging
    // compute-side B base: role-selected once (both are LDS)
    const bf16_t* const sBbase = half ? &sBZ[0][0] : &sBU[0][0];

    float st[4][2][4];             // U: u tile | Z: z tile (one role/thread)
    unsigned int eyp[4][2][2];     // Z only: e_y packed 2x bf16 per reg
    float esum = 0.0f;

    const bf16_t* Asrc = exA;
    bf16_t*       Adst = exB;

    for (int it = 0; it < NITER; ++it) {
        const bf16_t* gA = Asrc + (int64_t)(m0 + srow) * DIN + scol;
        f32x4 acc[4][2] = {};

        auto stage = [&](int tile, int buf) {
            const int64_t ko = (int64_t)tile * BK;
            if (half == 0) {
                GLDS(gA  + ko, &sA [buf][w8 * 512]);
                GLDS(gBu + ko, &sBU[buf][w8 * 512]);
            } else {
                GLDS(gBz + ko, &sBZ[buf][w8 * 512]);
            }
        };
        auto compute = [&](int buf) {
            bf16x8 af[4], bfr[2];
#pragma unroll
            for (int mi = 0; mi < 4; ++mi)
                af[mi] = *reinterpret_cast<const bf16x8*>(
                    &sA[buf][(wm * 64 + mi * 16 + lr) * BK + lkb]);
#pragma unroll
            for (int ni = 0; ni < 2; ++ni)
                bfr[ni] = *reinterpret_cast<const bf16x8*>(
                    &sBbase[buf * (BN * BK) +
                            (wn * 32 + ni * 16 + lr) * BK + lkb]);
#pragma unroll
            for (int mi = 0; mi < 4; ++mi)
#pragma unroll
                for (int ni = 0; ni < 2; ++ni)
                    acc[mi][ni] = __builtin_amdgcn_mfma_f32_16x16x32_bf16(
                        af[mi], bfr[ni], acc[mi][ni], 0, 0, 0);
        };

        const int npairs = (DIN / BK) / 2;   // 16
        stage(0, 0); stage(1, 1); stage(2, 2); stage(3, 3);
        for (int p = 0; p < npairs - 2; ++p) {
            const int t0 = 2 * p;
            if (half == 0) { WAITVM(4); } else { WAITVM(2); }
            BAR();
            SCHEDB();
            compute(t0 & 3);
            compute((t0 + 1) & 3);
            BAR();
            stage(t0 + 4, t0 & 3);       // never drain vmcnt to 0 in loop
            stage(t0 + 5, (t0 + 1) & 3);
        }
        {
            const int t0 = 2 * npairs - 4;
            if (half == 0) { WAITVM(4); } else { WAITVM(2); }
            BAR(); SCHEDB();
            compute(t0 & 3); compute((t0 + 1) & 3);
        }
        {
            const int t0 = 2 * npairs - 2;
            WAITVM(0); BAR(); SCHEDB();
            compute(t0 & 3); compute((t0 + 1) & 3);
        }

        // epilogue: C mapping col=lane&15, row=(lane>>4)*4+j
#pragma unroll
        for (int mi = 0; mi < 4; ++mi) {
#pragma unroll
            for (int ni = 0; ni < 2; ++ni) {
                const int col = n0 + wn * 32 + ni * 16 + lr;
#pragma unroll
                for (int j = 0; j < 4; ++j) {
                    const int row = m0 + wm * 64 + mi * 16 + prow + j;
                    const float D = LR * acc[mi][ni][j];
                    if (half == 0) {
                        if (it != NITER - 1) {   // e_x^(50) not needed/counted
                            const int64_t idx = (int64_t)row * DIN + col;
                            const float base = (it == 0) ? bias_g[col]
                                                         : st[mi][ni][j];
                            const float un = base + D;
                            st[mi][ni][j] = un;
                            const float xp = 1.0f / (1.0f + __expf(-un));
                            const float e  = xin[idx] - xp;
                            Adst[idx] = (bf16_t)e;
                            esum += e * e;
                        }
                    } else if (col < DOUT) {
                        const float base = (it == 0) ? bias_o[col]
                                                     : st[mi][ni][j];
                        const float zn = base + D;
                        st[mi][ni][j] = zn;
                        const unsigned int w = eyp[mi][ni][j >> 1];
                        const float eyold = bf16_val(
                            (j & 1) ? (unsigned short)(w >> 16)
                                    : (unsigned short)(w & 0xFFFFu));
                        const float eyn =
                            (it == 0) ? -zn : (1.0f + LR) * eyold - D;
                        if (it == NITER - 1) {
                            yout[(int64_t)row * DOUT + col] =
                                (1.0f + LR) * eyn + zn;
                        } else {
                            const unsigned int b = bf16_bits(eyn);
                            eyp[mi][ni][j >> 1] =
                                (j & 1) ? ((w & 0x0000FFFFu) | (b << 16))
                                        : ((w & 0xFFFF0000u) | b);
                        }
                        esum += eyn * eyn;
                    }
                }
            }
        }

        // ---- slice barrier: 8 blocks sharing m-slice, monotonic counter ---
        if (it != NITER - 1) {
            __syncthreads();
            if (t == 0) {
                __threadfence();                       // publish e_x' stores
                atomicAdd(&barcnt[m], 1u);
                const unsigned int tgt = 8u * (unsigned int)(it + 1);
                while (atomicAdd(&barcnt[m], 0u) < tgt)
                    __builtin_amdgcn_s_sleep(8);
                __threadfence();                       // acquire peers' stores
            }
            __syncthreads();
        }
        bf16_t* tmp = Adst; Adst = (bf16_t*)Asrc; Asrc = tmp;
    }

    // energy reduction: esum accumulated over all iterations
#pragma unroll
    for (int off = 32; off; off >>= 1) esum += __shfl_down(esum, off, 64);
    if (lane == 0) red[wave] = esum;
    __syncthreads();
    if (t == 0) {
        float s = 0.0f;
#pragma unroll
        for (int w = 0; w < 16; ++w) s += red[w];
        atomicAdd(energy, s);
    }
}

// ---------------------------------------------------------------------------
// setup: Wg = W_rec^T W_rec (role 0), Wc = W_out W_rec (role 1); K = 2048.
// R6-proven GEMM core, plain C-store epilogue.  Runs once.
// ---------------------------------------------------------------------------
__global__ __launch_bounds__(512) void setup_gemm(
    const bf16_t* __restrict__ wrecT, const bf16_t* __restrict__ woutP,
    bf16_t* __restrict__ wg, bf16_t* __restrict__ wc)
{
    __shared__ __align__(16) bf16_t sA[NBUF][BM * BK];
    __shared__ __align__(16) bf16_t sB[NBUF][BN * BK];

    const int t    = threadIdx.x;
    const int lane = t & 63;
    const int wave = t >> 6;
    const int wm   = wave >> 2;
    const int wn   = wave & 3;
    const int m0   = blockIdx.x * BM;
    const int role = (int)blockIdx.y >= 8;
    const int n0   = ((int)blockIdx.y & 7) * BN;
    const int lr   = lane & 15;
    const int lkb  = (lane >> 4) * 8;
    const int prow = (lane >> 4) * 4;

    f32x4 acc[4][2] = {};

    const int srow = wave * 16 + (lane >> 2);
    const int scol = (lane & 3) * 8;
    const bf16_t* gA = (role ? woutP : wrecT) + (int64_t)(m0 + srow) * HID + scol;
    const bf16_t* gB = wrecT + (int64_t)(n0 + srow) * HID + scol;

    auto stage = [&](int tile, int buf) {
        const int64_t ko = (int64_t)tile * BK;
        GLDS(gA + ko, &sA[buf][wave * 512]);
        GLDS(gB + ko, &sB[buf][wave * 512]);
    };
    auto compute = [&](int buf) {
        bf16x8 af[4], bfr[2];
#pragma unroll
        for (int mi = 0; mi < 4; ++mi)
            af[mi] = *reinterpret_cast<const bf16x8*>(
                &sA[buf][(wm * 64 + mi * 16 + lr) * BK + lkb]);
#pragma unroll
        for (int ni = 0; ni < 2; ++ni)
            bfr[ni] = *reinterpret_cast<const bf16x8*>(
                &sB[buf][(wn * 32 + ni * 16 + lr) * BK + lkb]);
#pragma unroll
        for (int mi = 0; mi < 4; ++mi)
#pragma unroll
            for (int ni = 0; ni < 2; ++ni)
                acc[mi][ni] = __builtin_amdgcn_mfma_f32_16x16x32_bf16(
                    af[mi], bfr[ni], acc[mi][ni], 0, 0, 0);
    };

    const int npairs = (HID / BK) / 2;   // 32
    stage(0, 0); stage(1, 1); stage(2, 2); stage(3, 3);
    for (int p = 0; p < npairs - 2; ++p) {
        const int t0 = 2 * p;
        WAITVM(4); BAR(); SCHEDB();
        compute(t0 & 3); compute((t0 + 1) & 3);
        BAR();
        stage(t0 + 4, t0 & 3); stage(t0 + 5, (t0 + 1) & 3);
    }
    {
        const int t0 = 2 * npairs - 4;
        WAITVM(4); BAR(); SCHEDB();
        compute(t0 & 3); compute((t0 + 1) & 3);
    }
    {
        const int t0 = 2 * npairs - 2;
        WAITVM(0); BAR(); SCHEDB();
        compute(t0 & 3); compute((t0 + 1) & 3);
    }

    bf16_t* cout = role ? wc : wg;
#pragma unroll
    for (int mi = 0; mi < 4; ++mi)
#pragma unroll
        for (int ni = 0; ni < 2; ++ni) {
            const int col = n0 + wn * 32 + ni * 16 + lr;
#pragma unroll
            for (int j = 0; j < 4; ++j) {
                const int row = m0 + wm * 64 + mi * 16 + prow + j;
                cout[(int64_t)row * 1024 + col] = (bf16_t)acc[mi][ni][j];
            }
        }
}

// W_rec [HID][DIN] f32 -> bf16 transpose [DIN][HID]
__global__ void conv_wrec(const float* __restrict__ W, bf16_t* __restrict__ WbT)
{
    __shared__ float tile[32][33];
    const int tx = threadIdx.x & 31;
    const int ty = threadIdx.x >> 5;
    const int c0 = blockIdx.x * 32;
    const int r0 = blockIdx.y * 32;
#pragma unroll
    for (int rr = ty; rr < 32; rr += 8)
        tile[rr][tx] = W[(int64_t)(r0 + rr) * DIN + c0 + tx];
    __syncthreads();
#pragma unroll
    for (int rr = ty; rr < 32; rr += 8)
        WbT[(int64_t)(c0 + rr) * HID + r0 + tx] = (bf16_t)tile[tx][rr];
}

// W_out [DOUT][HID] f32 -> bf16 [1024][HID], rows >= DOUT zero-padded
__global__ void conv_wout(const float* __restrict__ W, bf16_t* __restrict__ Wb)
{
    const int i = blockIdx.x * 256 + threadIdx.x;
    const int r = i >> 11;
    const int c = i & 2047;
    Wb[i] = (r < DOUT) ? (bf16_t)W[(int64_t)r * HID + c] : (bf16_t)0.0f;
}

// iteration 0: e_x_0 = x - sigmoid(b_gen), + its energy term
__global__ void ex0_kernel(const float* __restrict__ x,
                           const float* __restrict__ bias_g,
                           bf16_t* __restrict__ ex, float* __restrict__ energy)
{
    __shared__ float red[4];
    const int t = threadIdx.x, lane = t & 63, wave = t >> 6;
    const int i = (blockIdx.x * 256 + t) * 4;
    const int c0 = i & (DIN - 1);
    const float4 v = *reinterpret_cast<const float4*>(&x[i]);
    float e[4];
    const float b0 = bias_g[c0], b1 = bias_g[c0 + 1],
                b2 = bias_g[c0 + 2], b3 = bias_g[c0 + 3];
    e[0] = v.x - 1.0f / (1.0f + __expf(-b0));
    e[1] = v.y - 1.0f / (1.0f + __expf(-b1));
    e[2] = v.z - 1.0f / (1.0f + __expf(-b2));
    e[3] = v.w - 1.0f / (1.0f + __expf(-b3));
    bf16x4 o = {(bf16_t)e[0], (bf16_t)e[1], (bf16_t)e[2], (bf16_t)e[3]};
    *reinterpret_cast<bf16x4*>(&ex[i]) = o;
    float esum = e[0]*e[0] + e[1]*e[1] + e[2]*e[2] + e[3]*e[3];
#pragma unroll
    for (int off = 32; off; off >>= 1) esum += __shfl_down(esum, off, 64);
    if (lane == 0) red[wave] = esum;
    __syncthreads();
    if (t == 0) atomicAdd(energy, red[0] + red[1] + red[2] + red[3]);
}

__global__ void finalize_kernel(const float* __restrict__ energy,
                                float* __restrict__ out)
{
    out[0] = energy[0] * (1.0f / ((float)BATCH * (float)NITER));
}

extern "C" void kernel_launch(void* const* d_in, const int* in_sizes, int n_in,
                              void* d_out, int out_size, void* d_ws, size_t ws_size,
                              hipStream_t stream)
{
    (void)in_sizes; (void)n_in; (void)out_size; (void)ws_size;
    const float* x        = (const float*)d_in[0];
    const float* W_rec    = (const float*)d_in[1];
    const float* W_out    = (const float*)d_in[2];
    const float* bias_out = (const float*)d_in[3];
    const float* bias_gen = (const float*)d_in[4];
    float* y = (float*)d_out; // [BATCH*DOUT] then [1] energy

    char* ws = (char*)d_ws;
    size_t off = 0;
    bf16_t* exA   = (bf16_t*)(ws + off);  off += (size_t)BATCH * DIN * 2;   // 8 MB
    bf16_t* exB   = (bf16_t*)(ws + off);  off += (size_t)BATCH * DIN * 2;   // 8 MB
    bf16_t* wrecT = (bf16_t*)(ws + off);  off += (size_t)DIN * HID * 2;     // 4 MB
    bf16_t* woutP = (bf16_t*)(ws + off);  off += (size_t)1024 * HID * 2;    // 4 MB
    bf16_t* wg    = (bf16_t*)(ws + off);  off += (size_t)1024 * 1024 * 2;   // 2 MB
    bf16_t* wc    = (bf16_t*)(ws + off);  off += (size_t)1024 * 1024 * 2;   // 2 MB
    float* energy = (float*)(ws + off);                                     // +256 B
    unsigned int* barcnt = (unsigned int*)(ws + off + 64);  // 32 counters

    // zero energy + barrier counters (fresh every call -> deterministic)
    hipMemsetAsync(energy, 0, 256, stream);

    conv_wrec<<<dim3(DIN / 32, HID / 32), 256, 0, stream>>>(W_rec, wrecT);
    conv_wout<<<(1024 * HID) / 256, 256, 0, stream>>>(W_out, woutP);
    setup_gemm<<<dim3(8, 16), 512, 0, stream>>>(wrecT, woutP, wg, wc);
    ex0_kernel<<<(BATCH * DIN) / 1024, 256, 0, stream>>>(x, bias_gen, exA, energy);

    pc_persist<<<dim3(256), dim3(1024), 0, stream>>>(
        exA, exB, wg, wc, x, bias_gen, bias_out, y, energy, barcnt);

    finalize_kernel<<<1, 1, 0, stream>>>(energy, y + (size_t)BATCH * DOUT);
}